// Round 3
// baseline (937.088 us; speedup 1.0000x reference)
//
#include <hip/hip_runtime.h>
#include <hip/hip_bf16.h>

using bf16 = __hip_bfloat16;
typedef __bf16 bfrag __attribute__((ext_vector_type(8)));
typedef float  ffrag __attribute__((ext_vector_type(4)));

// Problem: B=32, N=8, Q=1536, K=256, CELL=128, EMB=32. Inputs f32, outputs f32.
// workspace layout (bytes)
#define WS_EO    0         // emb_o bf16 [256 key][32 e]                16 KB
#define WS_W2T   16384     // Wq2^T bf16 [32 e][256 h]                  16 KB
#define WS_W1T   32768     // Wq1^T bf16 [256 h][32 in-pad] (+bias k15) 16 KB
#define WS_WA1T  49152     // Wa1^T*ln2 bf16 [64 u][32 e]                4 KB
#define WS_VBF   65536     // view_cell bf16 [256 bn][128 c][256 k]     16 MB (optional)

#define LOG2E 1.44269504f
#define LN2   0.6931471805599453f

__device__ __forceinline__ float sigmoidf_(float x){ return 1.f/(1.f+__expf(-x)); }

__device__ __forceinline__ void relpose(const float* mo, const float* mq, float* o) {
  float a=mo[0],bb=mo[1],c=mo[2], d=mo[4],e=mo[5],f=mo[6], g=mo[8],h=mo[9],i9=mo[10];
  float A = e*i9-f*h, Bc = f*g-d*i9, C = d*h-e*g;
  float inv = 1.f/(a*A + bb*Bc + c*C);
  float r00=A*inv,  r01=(c*h-bb*i9)*inv, r02=(bb*f-c*e)*inv;
  float r10=Bc*inv, r11=(a*i9-c*g)*inv,  r12=(c*d-a*f)*inv;
  float r20=C*inv,  r21=(bb*g-a*h)*inv,  r22=(a*e-bb*d)*inv;
  float tx = mq[3]-mo[3], ty = mq[7]-mo[7], tz = mq[11]-mo[11];
  o[0]=r00*mq[0]+r01*mq[4]+r02*mq[8];  o[1]=r00*mq[1]+r01*mq[5]+r02*mq[9];
  o[2]=r00*mq[2]+r01*mq[6]+r02*mq[10]; o[3]=r00*tx+r01*ty+r02*tz;
  o[4]=r10*mq[0]+r11*mq[4]+r12*mq[8];  o[5]=r10*mq[1]+r11*mq[5]+r12*mq[9];
  o[6]=r10*mq[2]+r11*mq[6]+r12*mq[10]; o[7]=r10*tx+r11*ty+r12*tz;
  o[8]=r20*mq[0]+r21*mq[4]+r22*mq[8];  o[9]=r20*mq[1]+r21*mq[5]+r22*mq[9];
  o[10]=r20*mq[2]+r21*mq[6]+r22*mq[10]; o[11]=r20*tx+r21*ty+r22*tz;
}

__device__ __forceinline__ void quat7(const float* m, float* o) {
  float m00=m[0], m01=m[1], m02=m[2];
  float m10=m[4], m11=m[5], m12=m[6];
  float m20=m[8], m21=m[9], m22=m[10];
  float t,q0,q1,q2,q3;
  if (m22 < 0.f) {
    if (m00 > m11) { t=1.f+m00-m11-m22; q0=t;        q1=m01+m10; q2=m20+m02; q3=m12-m21; }
    else           { t=1.f-m00+m11-m22; q0=m01+m10; q1=t;        q2=m12+m21; q3=m20-m02; }
  } else {
    if (m00 < -m11){ t=1.f-m00-m11+m22; q0=m20+m02; q1=m12+m21; q2=t;        q3=m01-m10; }
    else           { t=1.f+m00+m11+m22; q0=m12-m21; q1=m20-m02; q2=m01-m10; q3=t;        }
  }
  float s = 0.5f / sqrtf(t);
  o[0]=m[3]; o[1]=m[7]; o[2]=m[11];
  o[3]=q0*s; o[4]=q1*s; o[5]=q2*s; o[6]=q3*s;
}

// ---------------- single prep kernel: vconv blocks + 5 parallel 1-block roles --------
__global__ void k_prep(const float* __restrict__ vc, bf16* __restrict__ vbf,
                       const float* __restrict__ pose_o, const float* __restrict__ pose_q,
                       const float* __restrict__ Wk1, const float* __restrict__ bk1,
                       const float* __restrict__ Wk2, const float* __restrict__ bk2,
                       const float* __restrict__ Wq1, const float* __restrict__ bq1,
                       const float* __restrict__ Wq2, const float* __restrict__ Wa1,
                       float* __restrict__ out_qo, float* __restrict__ out_qq,
                       bf16* __restrict__ ws_eo, bf16* __restrict__ ws_w2t,
                       bf16* __restrict__ ws_w1t, bf16* __restrict__ ws_wa1t,
                       int vblocks) {
  const int bid = blockIdx.x, tid = threadIdx.x;
  if (bid < vblocks) {   // view_cell f32 -> bf16
    int idx = (bid*256 + tid)*8;
    float4 a = *(const float4*)&vc[idx];
    float4 b = *(const float4*)&vc[idx+4];
    __bf16 o[8] __attribute__((aligned(16)));
    o[0]=(__bf16)a.x; o[1]=(__bf16)a.y; o[2]=(__bf16)a.z; o[3]=(__bf16)a.w;
    o[4]=(__bf16)b.x; o[5]=(__bf16)b.y; o[6]=(__bf16)b.z; o[7]=(__bf16)b.w;
    *(uint4*)&vbf[idx] = *(const uint4*)o;
    return;
  }
  const int role = bid - vblocks;
  if (role == 0) {          // quaternion outputs
    float mo[12];
    #pragma unroll
    for (int i=0;i<12;i++) mo[i] = pose_o[tid*12+i];
    float q7[7]; quat7(mo, q7);
    #pragma unroll
    for (int i=0;i<7;i++) out_qo[tid*7+i] = q7[i];
    if (tid < 32) {
      float mq[12];
      #pragma unroll
      for (int i=0;i<12;i++) mq[i] = pose_q[tid*12+i];
      float q7b[7]; quat7(mq, q7b);
      #pragma unroll
      for (int i=0;i<7;i++) out_qq[tid*7+i] = q7b[i];
    }
  } else if (role == 1) {   // key embeddings -> ws_eo [key][32]
    int k = tid;
    float x0 = -1.f + (float)(k>>4)*(2.f/15.f);
    float x1 = -1.f + (float)(k&15)*(2.f/15.f);
    float acc[32];
    #pragma unroll
    for (int e=0;e<32;e++) acc[e] = bk2[e];
    for (int j=0;j<128;j++) {
      float hj = fmaxf(fmaf(x0, Wk1[j], fmaf(x1, Wk1[128+j], bk1[j])), 0.f);
      #pragma unroll
      for (int u=0;u<8;u++) {
        float4 w = *(const float4*)&Wk2[j*32+u*4];
        acc[u*4+0] = fmaf(hj, w.x, acc[u*4+0]);
        acc[u*4+1] = fmaf(hj, w.y, acc[u*4+1]);
        acc[u*4+2] = fmaf(hj, w.z, acc[u*4+2]);
        acc[u*4+3] = fmaf(hj, w.w, acc[u*4+3]);
      }
    }
    #pragma unroll
    for (int e=0;e<32;e++) ws_eo[k*32+e] = __float2bfloat16(acc[e]);
  } else if (role == 2) {   // Wq2 [256h][32e] -> ws_w2t [e][h]
    int k = tid;
    #pragma unroll
    for (int u=0;u<8;u++) {
      float4 w = *(const float4*)&Wq2[k*32+u*4];
      ws_w2t[(u*4+0)*256+k] = __float2bfloat16(w.x);
      ws_w2t[(u*4+1)*256+k] = __float2bfloat16(w.y);
      ws_w2t[(u*4+2)*256+k] = __float2bfloat16(w.z);
      ws_w2t[(u*4+3)*256+k] = __float2bfloat16(w.w);
    }
  } else if (role == 3) {   // Wq1 [15][256] -> ws_w1t [h][32] with bias row k=15, 16..31 = 0
    int h = tid;
    bf16 row[32];
    #pragma unroll
    for (int i=0;i<15;i++) row[i] = __float2bfloat16(Wq1[i*256+h]);
    row[15] = __float2bfloat16(bq1[h]);
    #pragma unroll
    for (int i=16;i<32;i++) row[i] = __float2bfloat16(0.f);
    #pragma unroll
    for (int i=0;i<32;i++) ws_w1t[h*32+i] = row[i];
  } else {                  // Wa1 [32e][64u] -> ws_wa1t [u][e] * ln2 (emb is log2e-scaled)
    if (tid < 64) {
      #pragma unroll
      for (int e=0;e<32;e++) ws_wa1t[tid*32+e] = __float2bfloat16(Wa1[e*64+tid] * LN2);
    }
  }
}

// ---------------- k_main: 4 waves/block, each wave (qs,ch) fully wave-local ----------
// grid dim3(48,32). wave w: qs = w&1 (16 q's), ch = w>>1 (64 channels). P1-P3
// duplicated per ch-pair; ZERO barriers in the n-loop. Phase-3 softmax uses
// RECOMPUTE-S (two MFMA passes over eo) so only ~30 regs are live -> no spill
// (round-2's Sv[16] spill was the 280MB scratch + L2-thrash regression).
// Frag layouts (gfx950 16x16x32_bf16): A[m=l15][k=quad*8+j], B[k=quad*8+j][n=l15],
// D[m=quad*4+r][n=l15].
template<bool PRE>
__global__ void __launch_bounds__(256, 4)
k_main(const float* __restrict__ vc, const bf16* __restrict__ vbf_,
       const float* __restrict__ pose_o, const float* __restrict__ pose_q,
       const bf16* __restrict__ ws_eo_, const bf16* __restrict__ ws_w2t_,
       const bf16* __restrict__ ws_w1t_, const bf16* __restrict__ ws_wa1t_,
       const float* __restrict__ bq2,
       const float* __restrict__ ba1, const float* __restrict__ Wa2,
       const float* __restrict__ ba2,
       float* __restrict__ out) {
  __shared__ __align__(16) __bf16 s_hp[4][16*264];  // per-wave hidden -> expP  33.8 KB
  __shared__ __align__(16) __bf16 s_eq[4][16*40];   // per-wave emb_q'           5.0 KB
  __shared__ __align__(16) float  s_pt[96];         // relpose [8][12]

  const __bf16* vbf  = (const __bf16*)vbf_;
  const __bf16* eo   = (const __bf16*)ws_eo_;
  const __bf16* w2t  = (const __bf16*)ws_w2t_;
  const __bf16* w1t  = (const __bf16*)ws_w1t_;
  const __bf16* wa1t = (const __bf16*)ws_wa1t_;

  const int tid  = threadIdx.x;
  const int w    = tid >> 6;
  const int lane = tid & 63;
  const int quad = lane >> 4;
  const int l15  = lane & 15;
  const int qs   = w & 1;        // which 16-q half this wave owns
  const int ch   = w >> 1;       // which 64-channel half this wave owns
  const int b    = blockIdx.y;
  const int qt0  = blockIdx.x * 32;

  __bf16* myhp = s_hp[w];
  __bf16* myeq = s_eq[w];

  // ---- one-time staging (only barrier in the kernel) ----
  if (tid < 8) {
    float mo[12], mq[12], pt[12];
    #pragma unroll
    for (int i=0;i<12;i++) mo[i] = pose_o[(b*8+tid)*12+i];
    #pragma unroll
    for (int i=0;i<12;i++) mq[i] = pose_q[b*12+i];
    relpose(mo, mq, pt);
    #pragma unroll
    for (int i=0;i<12;i++) s_pt[tid*12+i] = pt[i];
  }
  __syncthreads();

  // ---- hoisted per-lane constants ----
  const int qg = qt0 + qs*16 + l15;
  const float c0 = (float)(qg>>8) * 0.2f;
  const float c1 = -1.f + (float)((qg>>4)&15)*(2.f/15.f);
  const float c2 = -1.f + (float)(qg&15)*(2.f/15.f);
  const float bq2s0 = bq2[l15]    * LOG2E;   // et=0 bias (log2-domain)
  const float bq2s1 = bq2[16+l15] * LOG2E;   // et=1
  const float ba2v  = ba2[0];

  ffrag acc[4];
  #pragma unroll
  for (int ct=0;ct<4;ct++) acc[ct] = (ffrag){0.f,0.f,0.f,0.f};

  #pragma unroll 1
  for (int n=0; n<8; n++) {
    const int bn = b*8 + n;
    // ---- phase 1: hidden D[h][q] = W1^T @ X (K=32), 16 h-tiles, own qs ----
    {
      float4 pa = *(const float4*)&s_pt[n*12];
      float4 pb = *(const float4*)&s_pt[n*12+4];
      float4 pc = *(const float4*)&s_pt[n*12+8];
      bfrag Bx;
      if (quad == 0) {
        Bx[0]=(__bf16)pa.x; Bx[1]=(__bf16)pa.y; Bx[2]=(__bf16)pa.z; Bx[3]=(__bf16)pa.w;
        Bx[4]=(__bf16)pb.x; Bx[5]=(__bf16)pb.y; Bx[6]=(__bf16)pb.z; Bx[7]=(__bf16)pb.w;
      } else if (quad == 1) {
        Bx[0]=(__bf16)pc.x; Bx[1]=(__bf16)pc.y; Bx[2]=(__bf16)pc.z; Bx[3]=(__bf16)pc.w;
        Bx[4]=(__bf16)c0; Bx[5]=(__bf16)c1; Bx[6]=(__bf16)c2; Bx[7]=(__bf16)1.f;
      } else {
        #pragma unroll
        for (int j=0;j<8;j++) Bx[j]=(__bf16)0.f;
      }
      #pragma unroll
      for (int t=0;t<16;t++) {
        bfrag A = *(const bfrag*)&w1t[(t*16+l15)*32 + quad*8];
        ffrag C = {0.f,0.f,0.f,0.f};
        C = __builtin_amdgcn_mfma_f32_16x16x32_bf16(A, Bx, C, 0, 0, 0);
        __bf16 p[4] __attribute__((aligned(8)));
        #pragma unroll
        for (int r=0;r<4;r++) p[r] = (__bf16)fmaxf(C[r], 0.f);
        *(uint2*)&myhp[l15*264 + t*16 + quad*4] = *(const uint2*)p;
      }
    }
    // ---- phase 2: emb'[q][e] = (hidden @ W2 + bq2)*log2e, K=256, own qs ----
    {
      ffrag C2[2];
      C2[0]=(ffrag){0.f,0.f,0.f,0.f}; C2[1]=(ffrag){0.f,0.f,0.f,0.f};
      #pragma unroll
      for (int s=0;s<8;s++) {
        bfrag A  = *(const bfrag*)&myhp[l15*264 + s*32 + quad*8];
        bfrag B0 = *(const bfrag*)&w2t[l15*256      + s*32 + quad*8];
        bfrag B1 = *(const bfrag*)&w2t[(16+l15)*256 + s*32 + quad*8];
        C2[0] = __builtin_amdgcn_mfma_f32_16x16x32_bf16(A, B0, C2[0], 0, 0, 0);
        C2[1] = __builtin_amdgcn_mfma_f32_16x16x32_bf16(A, B1, C2[1], 0, 0, 0);
      }
      #pragma unroll
      for (int et=0;et<2;et++)
        #pragma unroll
        for (int r=0;r<4;r++) {
          float es = fmaf(C2[et][r], LOG2E, et ? bq2s1 : bq2s0);
          myeq[(quad*4+r)*40 + et*16 + l15] = (__bf16)es;
        }
    }
    // ---- phase 3: mask + logits + softmax, intra-wave, recompute-S (no Sv array) ----
    bfrag Bq = *(const bfrag*)&myeq[l15*40 + quad*8];
    float msum = 0.f;
    #pragma unroll
    for (int ut=0; ut<4; ut++) {
      bfrag Aw = *(const bfrag*)&wa1t[(ut*16+l15)*32 + quad*8];
      ffrag Cm = {0.f,0.f,0.f,0.f};
      Cm = __builtin_amdgcn_mfma_f32_16x16x32_bf16(Aw, Bq, Cm, 0, 0, 0);
      float4 bav = *(const float4*)&ba1[ut*16 + quad*4];
      float4 wav = *(const float4*)&Wa2[ut*16 + quad*4];
      msum = fmaf(fmaxf(Cm[0]+bav.x,0.f), wav.x, msum);
      msum = fmaf(fmaxf(Cm[1]+bav.y,0.f), wav.y, msum);
      msum = fmaf(fmaxf(Cm[2]+bav.z,0.f), wav.z, msum);
      msum = fmaf(fmaxf(Cm[3]+bav.w,0.f), wav.w, msum);
    }
    msum += __shfl_xor(msum, 16);
    msum += __shfl_xor(msum, 32);
    // pass 1: row max (S discarded -> ~30 live regs, no spill)
    float mx = -1e30f;
    #pragma unroll
    for (int t=0;t<16;t++) {
      bfrag Ae = *(const bfrag*)&eo[(t*16+l15)*32 + quad*8];
      ffrag S = {0.f,0.f,0.f,0.f};
      S = __builtin_amdgcn_mfma_f32_16x16x32_bf16(Ae, Bq, S, 0, 0, 0);
      mx = fmaxf(mx, fmaxf(fmaxf(S[0], S[1]), fmaxf(S[2], S[3])));
    }
    mx = fmaxf(mx, __shfl_xor(mx, 16));
    mx = fmaxf(mx, __shfl_xor(mx, 32));
    // pass 2: recompute S (bit-identical), exp2, store P, sum
    float ps = 0.f;
    #pragma unroll
    for (int t=0;t<16;t++) {
      bfrag Ae = *(const bfrag*)&eo[(t*16+l15)*32 + quad*8];
      ffrag S = {0.f,0.f,0.f,0.f};
      S = __builtin_amdgcn_mfma_f32_16x16x32_bf16(Ae, Bq, S, 0, 0, 0);
      __bf16 p[4] __attribute__((aligned(8)));
      #pragma unroll
      for (int r=0;r<4;r++) {
        float e = exp2f(S[r] - mx);         // logits are log2e-scaled -> native v_exp
        ps += e;
        p[r] = (__bf16)e;
      }
      *(uint2*)&myhp[l15*264 + t*16 + quad*4] = *(const uint2*)p;  // overwrite hidden
    }
    ps += __shfl_xor(ps, 16);
    ps += __shfl_xor(ps, 32);
    const float rs = sigmoidf_(msum + ba2v) / ps;
    // ---- phase 4: vatt D[c][q] = V^T @ P^T, 4 c-tiles (own ch half), own qs ----
    {
      bfrag Bp[8];
      #pragma unroll
      for (int s=0;s<8;s++) Bp[s] = *(const bfrag*)&myhp[l15*264 + s*32 + quad*8];
      #pragma unroll
      for (int ct=0;ct<4;ct++) {
        const int crow = ch*64 + ct*16 + l15;
        ffrag Cv = {0.f,0.f,0.f,0.f};
        #pragma unroll
        for (int s=0;s<8;s++) {
          bfrag Av;
          if (PRE) {
            Av = *(const bfrag*)&vbf[((size_t)bn<<15) + crow*256 + s*32 + quad*8];
          } else {
            const float* p0 = &vc[((size_t)bn<<15) + crow*256 + s*32 + quad*8];
            float4 a0 = *(const float4*)p0, a1 = *(const float4*)(p0+4);
            Av[0]=(__bf16)a0.x; Av[1]=(__bf16)a0.y; Av[2]=(__bf16)a0.z; Av[3]=(__bf16)a0.w;
            Av[4]=(__bf16)a1.x; Av[5]=(__bf16)a1.y; Av[6]=(__bf16)a1.z; Av[7]=(__bf16)a1.w;
          }
          Cv = __builtin_amdgcn_mfma_f32_16x16x32_bf16(Av, Bp[s], Cv, 0, 0, 0);
        }
        #pragma unroll
        for (int r=0;r<4;r++) acc[ct][r] = fmaf(rs, Cv[r], acc[ct][r]);
      }
    }
  }
  // ---- epilogue: direct coalesced stores (16 lanes consecutive q = 64 B) ----
  #pragma unroll
  for (int ct=0;ct<4;ct++) {
    #pragma unroll
    for (int r=0;r<4;r++) {
      int c = ch*64 + ct*16 + quad*4 + r;
      out[(size_t)b*196608 + (size_t)c*1536 + qt0 + qs*16 + l15] = sigmoidf_(acc[ct][r]);
    }
  }
}

extern "C" void kernel_launch(void* const* d_in, const int* in_sizes, int n_in,
                              void* d_out, int out_size, void* d_ws, size_t ws_size,
                              hipStream_t stream) {
  const float* view_cell = (const float*)d_in[0];
  const float* pose_o = (const float*)d_in[1];
  const float* pose_q = (const float*)d_in[2];
  const float* Wk1 = (const float*)d_in[3];
  const float* bk1 = (const float*)d_in[4];
  const float* Wk2 = (const float*)d_in[5];
  const float* bk2 = (const float*)d_in[6];
  const float* Wq1 = (const float*)d_in[7];
  const float* bq1 = (const float*)d_in[8];
  const float* Wq2 = (const float*)d_in[9];
  const float* bq2 = (const float*)d_in[10];
  const float* Wa1 = (const float*)d_in[11];
  const float* ba1 = (const float*)d_in[12];
  const float* Wa2 = (const float*)d_in[13];
  const float* ba2 = (const float*)d_in[14];

  float* out = (float*)d_out;
  float* out_qo = out + 6291456;
  float* out_qq = out + 6291456 + 1792;

  bf16* ws_eo   = (bf16*)((char*)d_ws + WS_EO);
  bf16* ws_w2t  = (bf16*)((char*)d_ws + WS_W2T);
  bf16* ws_w1t  = (bf16*)((char*)d_ws + WS_W1T);
  bf16* ws_wa1t = (bf16*)((char*)d_ws + WS_WA1T);
  bf16* ws_vbf  = (bf16*)((char*)d_ws + WS_VBF);

  const bool pre = ws_size >= (size_t)(WS_VBF + 256u*128u*256u*2u);
  const int vblocks = pre ? 4096 : 0;

  hipLaunchKernelGGL(k_prep, dim3(vblocks + 5), dim3(256), 0, stream,
                     view_cell, ws_vbf, pose_o, pose_q, Wk1, bk1, Wk2, bk2,
                     Wq1, bq1, Wq2, Wa1, out_qo, out_qq,
                     ws_eo, ws_w2t, ws_w1t, ws_wa1t, vblocks);

  if (pre) {
    hipLaunchKernelGGL((k_main<true>), dim3(48, 32), dim3(256), 0, stream,
                       view_cell, ws_vbf, pose_o, pose_q, ws_eo, ws_w2t,
                       ws_w1t, ws_wa1t, bq2, ba1, Wa2, ba2, out);
  } else {
    hipLaunchKernelGGL((k_main<false>), dim3(48, 32), dim3(256), 0, stream,
                       view_cell, ws_vbf, pose_o, pose_q, ws_eo, ws_w2t,
                       ws_w1t, ws_wa1t, bq2, ba1, Wa2, ba2, out);
  }
}

// Round 5
// 641.412 us; speedup vs baseline: 1.4610x; 1.4610x over previous
//
#include <hip/hip_runtime.h>
#include <hip/hip_bf16.h>

using bf16 = __hip_bfloat16;
typedef __bf16 bfrag __attribute__((ext_vector_type(8)));
typedef float  ffrag __attribute__((ext_vector_type(4)));

// Problem: B=32, N=8, Q=1536, K=256, CELL=128, EMB=32. Inputs f32, outputs f32.
// workspace layout (bytes)
#define WS_EO    0         // emb_o bf16 [256 key][32 e]                16 KB
#define WS_W2T   16384     // Wq2^T bf16 [32 e][256 h]                  16 KB
#define WS_W1T   32768     // Wq1^T bf16 [256 h][32 in-pad] (+bias k15) 16 KB
#define WS_WA1T  49152     // Wa1^T*ln2 bf16 [64 u][32 e]                4 KB
#define WS_VBF   65536     // view_cell bf16 [256 bn][128 c][256 k]     16 MB (optional)

#define LOG2E 1.44269504f
#define LN2   0.6931471805599453f

__device__ __forceinline__ float sigmoidf_(float x){ return 1.f/(1.f+__expf(-x)); }

__device__ __forceinline__ void relpose(const float* mo, const float* mq, float* o) {
  float a=mo[0],bb=mo[1],c=mo[2], d=mo[4],e=mo[5],f=mo[6], g=mo[8],h=mo[9],i9=mo[10];
  float A = e*i9-f*h, Bc = f*g-d*i9, C = d*h-e*g;
  float inv = 1.f/(a*A + bb*Bc + c*C);
  float r00=A*inv,  r01=(c*h-bb*i9)*inv, r02=(bb*f-c*e)*inv;
  float r10=Bc*inv, r11=(a*i9-c*g)*inv,  r12=(c*d-a*f)*inv;
  float r20=C*inv,  r21=(bb*g-a*h)*inv,  r22=(a*e-bb*d)*inv;
  float tx = mq[3]-mo[3], ty = mq[7]-mo[7], tz = mq[11]-mo[11];
  o[0]=r00*mq[0]+r01*mq[4]+r02*mq[8];  o[1]=r00*mq[1]+r01*mq[5]+r02*mq[9];
  o[2]=r00*mq[2]+r01*mq[6]+r02*mq[10]; o[3]=r00*tx+r01*ty+r02*tz;
  o[4]=r10*mq[0]+r11*mq[4]+r12*mq[8];  o[5]=r10*mq[1]+r11*mq[5]+r12*mq[9];
  o[6]=r10*mq[2]+r11*mq[6]+r12*mq[10]; o[7]=r10*tx+r11*ty+r12*tz;
  o[8]=r20*mq[0]+r21*mq[4]+r22*mq[8];  o[9]=r20*mq[1]+r21*mq[5]+r22*mq[9];
  o[10]=r20*mq[2]+r21*mq[6]+r22*mq[10]; o[11]=r20*tx+r21*ty+r22*tz;
}

__device__ __forceinline__ void quat7(const float* m, float* o) {
  float m00=m[0], m01=m[1], m02=m[2];
  float m10=m[4], m11=m[5], m12=m[6];
  float m20=m[8], m21=m[9], m22=m[10];
  float t,q0,q1,q2,q3;
  if (m22 < 0.f) {
    if (m00 > m11) { t=1.f+m00-m11-m22; q0=t;        q1=m01+m10; q2=m20+m02; q3=m12-m21; }
    else           { t=1.f-m00+m11-m22; q0=m01+m10; q1=t;        q2=m12+m21; q3=m20-m02; }
  } else {
    if (m00 < -m11){ t=1.f-m00-m11+m22; q0=m20+m02; q1=m12+m21; q2=t;        q3=m01-m10; }
    else           { t=1.f+m00+m11+m22; q0=m12-m21; q1=m20-m02; q2=m01-m10; q3=t;        }
  }
  float s = 0.5f / sqrtf(t);
  o[0]=m[3]; o[1]=m[7]; o[2]=m[11];
  o[3]=q0*s; o[4]=q1*s; o[5]=q2*s; o[6]=q3*s;
}

// ---------------- single prep kernel: vconv blocks + 5 parallel 1-block roles --------
__global__ void k_prep(const float* __restrict__ vc, bf16* __restrict__ vbf,
                       const float* __restrict__ pose_o, const float* __restrict__ pose_q,
                       const float* __restrict__ Wk1, const float* __restrict__ bk1,
                       const float* __restrict__ Wk2, const float* __restrict__ bk2,
                       const float* __restrict__ Wq1, const float* __restrict__ bq1,
                       const float* __restrict__ Wq2, const float* __restrict__ Wa1,
                       float* __restrict__ out_qo, float* __restrict__ out_qq,
                       bf16* __restrict__ ws_eo, bf16* __restrict__ ws_w2t,
                       bf16* __restrict__ ws_w1t, bf16* __restrict__ ws_wa1t,
                       int vblocks) {
  const int bid = blockIdx.x, tid = threadIdx.x;
  if (bid < vblocks) {   // view_cell f32 -> bf16
    int idx = (bid*256 + tid)*8;
    float4 a = *(const float4*)&vc[idx];
    float4 b = *(const float4*)&vc[idx+4];
    __bf16 o[8] __attribute__((aligned(16)));
    o[0]=(__bf16)a.x; o[1]=(__bf16)a.y; o[2]=(__bf16)a.z; o[3]=(__bf16)a.w;
    o[4]=(__bf16)b.x; o[5]=(__bf16)b.y; o[6]=(__bf16)b.z; o[7]=(__bf16)b.w;
    *(uint4*)&vbf[idx] = *(const uint4*)o;
    return;
  }
  const int role = bid - vblocks;
  if (role == 0) {          // quaternion outputs
    float mo[12];
    #pragma unroll
    for (int i=0;i<12;i++) mo[i] = pose_o[tid*12+i];
    float q7[7]; quat7(mo, q7);
    #pragma unroll
    for (int i=0;i<7;i++) out_qo[tid*7+i] = q7[i];
    if (tid < 32) {
      float mq[12];
      #pragma unroll
      for (int i=0;i<12;i++) mq[i] = pose_q[tid*12+i];
      float q7b[7]; quat7(mq, q7b);
      #pragma unroll
      for (int i=0;i<7;i++) out_qq[tid*7+i] = q7b[i];
    }
  } else if (role == 1) {   // key embeddings -> ws_eo [key][32]
    int k = tid;
    float x0 = -1.f + (float)(k>>4)*(2.f/15.f);
    float x1 = -1.f + (float)(k&15)*(2.f/15.f);
    float acc[32];
    #pragma unroll
    for (int e=0;e<32;e++) acc[e] = bk2[e];
    for (int j=0;j<128;j++) {
      float hj = fmaxf(fmaf(x0, Wk1[j], fmaf(x1, Wk1[128+j], bk1[j])), 0.f);
      #pragma unroll
      for (int u=0;u<8;u++) {
        float4 w = *(const float4*)&Wk2[j*32+u*4];
        acc[u*4+0] = fmaf(hj, w.x, acc[u*4+0]);
        acc[u*4+1] = fmaf(hj, w.y, acc[u*4+1]);
        acc[u*4+2] = fmaf(hj, w.z, acc[u*4+2]);
        acc[u*4+3] = fmaf(hj, w.w, acc[u*4+3]);
      }
    }
    #pragma unroll
    for (int e=0;e<32;e++) ws_eo[k*32+e] = __float2bfloat16(acc[e]);
  } else if (role == 2) {   // Wq2 [256h][32e] -> ws_w2t [e][h]
    int k = tid;
    #pragma unroll
    for (int u=0;u<8;u++) {
      float4 w = *(const float4*)&Wq2[k*32+u*4];
      ws_w2t[(u*4+0)*256+k] = __float2bfloat16(w.x);
      ws_w2t[(u*4+1)*256+k] = __float2bfloat16(w.y);
      ws_w2t[(u*4+2)*256+k] = __float2bfloat16(w.z);
      ws_w2t[(u*4+3)*256+k] = __float2bfloat16(w.w);
    }
  } else if (role == 3) {   // Wq1 [15][256] -> ws_w1t [h][32] with bias row k=15, 16..31 = 0
    int h = tid;
    bf16 row[32];
    #pragma unroll
    for (int i=0;i<15;i++) row[i] = __float2bfloat16(Wq1[i*256+h]);
    row[15] = __float2bfloat16(bq1[h]);
    #pragma unroll
    for (int i=16;i<32;i++) row[i] = __float2bfloat16(0.f);
    #pragma unroll
    for (int i=0;i<32;i++) ws_w1t[h*32+i] = row[i];
  } else {                  // Wa1 [32e][64u] -> ws_wa1t [u][e] * ln2 (emb is log2e-scaled)
    if (tid < 64) {
      #pragma unroll
      for (int e=0;e<32;e++) ws_wa1t[tid*32+e] = __float2bfloat16(Wa1[e*64+tid] * LN2);
    }
  }
}

// ---------------- k_main: hybrid — R0's cross-wave P1/P2 (2 barriers), wave-local P3/P4
// grid dim3(48,32), 4 waves. wave w: qs = w&1 (its 16 q's in P3/P4), ch = w>>1 (its 64
// channels in P4). Barriers per n: B1 (s_h write->read; also protects s_eq from prev-n
// readers), B2 (s_eq write->read; also protects s_h for next-n writers). P3 softmax is
// recompute-S with an explicit CSE-breaker so only one S-frag is ever live (round-2/3's
// spill was Sv[16] / compiler-CSE'd equivalent). launch_bounds(256,3): the only bound
// that has never spilled (R0: VGPR 84, WRITE 24.6MB).
// Frag layouts (gfx950 16x16x32_bf16): A[m=l15][k=quad*8+j], B[k=quad*8+j][n=l15],
// D[m=quad*4+r][n=l15].
template<bool PRE>
__global__ void __launch_bounds__(256, 3)
k_main(const float* __restrict__ vc, const bf16* __restrict__ vbf_,
       const float* __restrict__ pose_o, const float* __restrict__ pose_q,
       const bf16* __restrict__ ws_eo_, const bf16* __restrict__ ws_w2t_,
       const bf16* __restrict__ ws_w1t_, const bf16* __restrict__ ws_wa1t_,
       const float* __restrict__ bq2,
       const float* __restrict__ ba1, const float* __restrict__ Wa2,
       const float* __restrict__ ba2,
       float* __restrict__ out) {
  __shared__ __align__(16) __bf16 s_h[32*264];      // hidden [q][h], cross-wave 16896 B
  __shared__ __align__(16) __bf16 s_p[4][16*264];   // expP, per-wave          33792 B
  __shared__ __align__(16) __bf16 s_eq[32*40];      // emb_q' [q][e], cross-wave 2560 B
  __shared__ __align__(16) float  s_pt[96];         // relpose [8][12]           384 B
  __shared__ float s_bw[128];                       // ba1[0..63], Wa2[64..127]  512 B
  // total 54144 B <= 54613 (3 blocks/CU)

  const __bf16* vbf  = (const __bf16*)vbf_;
  const __bf16* eo   = (const __bf16*)ws_eo_;
  const __bf16* w2t  = (const __bf16*)ws_w2t_;
  const __bf16* w1t  = (const __bf16*)ws_w1t_;
  const __bf16* wa1t = (const __bf16*)ws_wa1t_;

  const int tid  = threadIdx.x;
  const int w    = tid >> 6;
  const int lane = tid & 63;
  const int quad = lane >> 4;
  const int l15  = lane & 15;
  const int qs   = w & 1;        // wave's q-half for P3/P4
  const int ch   = w >> 1;       // wave's channel-half for P4
  const int b    = blockIdx.y;
  const int qt0  = blockIdx.x * 32;

  __bf16* myp = s_p[w];

  // ---- one-time staging ----
  if (tid < 8) {
    float mo[12], mq[12], pt[12];
    #pragma unroll
    for (int i=0;i<12;i++) mo[i] = pose_o[(b*8+tid)*12+i];
    #pragma unroll
    for (int i=0;i<12;i++) mq[i] = pose_q[b*12+i];
    relpose(mo, mq, pt);
    #pragma unroll
    for (int i=0;i<12;i++) s_pt[tid*12+i] = pt[i];
  }
  if (tid < 64) s_bw[tid] = ba1[tid];
  else if (tid < 128) s_bw[tid] = Wa2[tid-64];
  __syncthreads();

  // ---- hoisted per-lane constants ----
  float c012[2][3];
  #pragma unroll
  for (int q2=0;q2<2;q2++) {
    int qg = qt0 + q2*16 + l15;
    c012[q2][0] = (float)(qg>>8) * 0.2f;
    c012[q2][1] = -1.f + (float)((qg>>4)&15)*(2.f/15.f);
    c012[q2][2] = -1.f + (float)(qg&15)*(2.f/15.f);
  }
  const float bq2s = bq2[(w>>1)*16 + l15] * LOG2E;  // bias for the wave's P2 et-column
  const float ba2v = ba2[0];

  ffrag acc[4];
  #pragma unroll
  for (int ct=0;ct<4;ct++) acc[ct] = (ffrag){0.f,0.f,0.f,0.f};

  #pragma unroll 1
  for (int n=0; n<8; n++) {
    const int bn = b*8 + n;
    // ---- phase 1 (cross-wave, R0): hidden D[h][q], wave w does h-tiles w*4..w*4+3,
    //      both q-halves ----
    {
      float4 pa = *(const float4*)&s_pt[n*12];
      float4 pb = *(const float4*)&s_pt[n*12+4];
      float4 pc = *(const float4*)&s_pt[n*12+8];
      bfrag Bx[2];
      #pragma unroll
      for (int q2=0;q2<2;q2++) {
        bfrag x;
        if (quad == 0) {
          x[0]=(__bf16)pa.x; x[1]=(__bf16)pa.y; x[2]=(__bf16)pa.z; x[3]=(__bf16)pa.w;
          x[4]=(__bf16)pb.x; x[5]=(__bf16)pb.y; x[6]=(__bf16)pb.z; x[7]=(__bf16)pb.w;
        } else if (quad == 1) {
          x[0]=(__bf16)pc.x; x[1]=(__bf16)pc.y; x[2]=(__bf16)pc.z; x[3]=(__bf16)pc.w;
          x[4]=(__bf16)c012[q2][0]; x[5]=(__bf16)c012[q2][1];
          x[6]=(__bf16)c012[q2][2]; x[7]=(__bf16)1.f;
        } else {
          #pragma unroll
          for (int j=0;j<8;j++) x[j]=(__bf16)0.f;
        }
        Bx[q2] = x;
      }
      #pragma unroll
      for (int t=0;t<4;t++) {
        bfrag A = *(const bfrag*)&w1t[((w*4+t)*16+l15)*32 + quad*8];
        #pragma unroll
        for (int q2=0;q2<2;q2++) {
          ffrag C = {0.f,0.f,0.f,0.f};
          C = __builtin_amdgcn_mfma_f32_16x16x32_bf16(A, Bx[q2], C, 0, 0, 0);
          __bf16 p[4] __attribute__((aligned(8)));
          #pragma unroll
          for (int r=0;r<4;r++) p[r] = (__bf16)fmaxf(C[r], 0.f);
          *(uint2*)&s_h[(q2*16+l15)*264 + (w*4+t)*16 + quad*4] = *(const uint2*)p;
        }
      }
    }
    __syncthreads();                                   // B1
    // ---- phase 2 (cross-wave, R0): combo (qs2=w&1, et=w>>1), K=256 ----
    {
      const int et = w >> 1;
      ffrag C2 = {0.f,0.f,0.f,0.f};
      #pragma unroll
      for (int s=0;s<8;s++) {
        bfrag A  = *(const bfrag*)&s_h[(qs*16+l15)*264 + s*32 + quad*8];
        bfrag Bw = *(const bfrag*)&w2t[(et*16+l15)*256 + s*32 + quad*8];
        C2 = __builtin_amdgcn_mfma_f32_16x16x32_bf16(A, Bw, C2, 0, 0, 0);
      }
      #pragma unroll
      for (int r=0;r<4;r++) {
        float es = fmaf(C2[r], LOG2E, bq2s);
        s_eq[(qs*16+quad*4+r)*40 + et*16 + l15] = (__bf16)es;
      }
    }
    __syncthreads();                                   // B2
    // ---- phase 3 (wave-local): mask + logits + softmax for own qs ----
    bfrag Bq = *(const bfrag*)&s_eq[(qs*16+l15)*40 + quad*8];
    float msum = 0.f;
    #pragma unroll
    for (int ut=0; ut<4; ut++) {
      bfrag Aw = *(const bfrag*)&wa1t[(ut*16+l15)*32 + quad*8];
      ffrag Cm = {0.f,0.f,0.f,0.f};
      Cm = __builtin_amdgcn_mfma_f32_16x16x32_bf16(Aw, Bq, Cm, 0, 0, 0);
      float4 bav = *(const float4*)&s_bw[ut*16 + quad*4];
      float4 wav = *(const float4*)&s_bw[64 + ut*16 + quad*4];
      msum = fmaf(fmaxf(Cm[0]+bav.x,0.f), wav.x, msum);
      msum = fmaf(fmaxf(Cm[1]+bav.y,0.f), wav.y, msum);
      msum = fmaf(fmaxf(Cm[2]+bav.z,0.f), wav.z, msum);
      msum = fmaf(fmaxf(Cm[3]+bav.w,0.f), wav.w, msum);
    }
    msum += __shfl_xor(msum, 16);
    msum += __shfl_xor(msum, 32);
    // pass 1: row max (S discarded; only one frag live)
    float mx = -1e30f;
    #pragma unroll
    for (int t=0;t<16;t++) {
      bfrag Ae = *(const bfrag*)&eo[(t*16+l15)*32 + quad*8];
      ffrag S = {0.f,0.f,0.f,0.f};
      S = __builtin_amdgcn_mfma_f32_16x16x32_bf16(Ae, Bq, S, 0, 0, 0);
      mx = fmaxf(mx, fmaxf(fmaxf(S[0], S[1]), fmaxf(S[2], S[3])));
    }
    mx = fmaxf(mx, __shfl_xor(mx, 16));
    mx = fmaxf(mx, __shfl_xor(mx, 32));
    // CSE-breaker: memory clobber + Bq reload so pass-2 MFMAs cannot be unified with
    // pass-1 (round-3 lesson: otherwise LLVM keeps all 64 logits live and spills).
    asm volatile("" ::: "memory");
    Bq = *(const bfrag*)&s_eq[(qs*16+l15)*40 + quad*8];
    // pass 2: recompute S, exp2, store P, sum
    float ps = 0.f;
    #pragma unroll
    for (int t=0;t<16;t++) {
      bfrag Ae = *(const bfrag*)&eo[(t*16+l15)*32 + quad*8];
      ffrag S = {0.f,0.f,0.f,0.f};
      S = __builtin_amdgcn_mfma_f32_16x16x32_bf16(Ae, Bq, S, 0, 0, 0);
      __bf16 p[4] __attribute__((aligned(8)));
      #pragma unroll
      for (int r=0;r<4;r++) {
        float e = exp2f(S[r] - mx);         // logits are log2e-scaled -> native v_exp
        ps += e;
        p[r] = (__bf16)e;
      }
      *(uint2*)&myp[l15*264 + t*16 + quad*4] = *(const uint2*)p;
    }
    ps += __shfl_xor(ps, 16);
    ps += __shfl_xor(ps, 32);
    const float rs = sigmoidf_(msum + ba2v) / ps;
    // ---- phase 4 (wave-local): vatt D[c][q], own ch half x own qs ----
    {
      ffrag Cv[4];
      #pragma unroll
      for (int ct=0;ct<4;ct++) Cv[ct] = (ffrag){0.f,0.f,0.f,0.f};
      #pragma unroll
      for (int s=0;s<8;s++) {
        bfrag Bp = *(const bfrag*)&myp[l15*264 + s*32 + quad*8];
        #pragma unroll
        for (int ct=0;ct<4;ct++) {
          const int crow = ch*64 + ct*16 + l15;
          bfrag Av;
          if (PRE) {
            Av = *(const bfrag*)&vbf[((size_t)bn<<15) + crow*256 + s*32 + quad*8];
          } else {
            const float* p0 = &vc[((size_t)bn<<15) + crow*256 + s*32 + quad*8];
            float4 a0 = *(const float4*)p0, a1 = *(const float4*)(p0+4);
            Av[0]=(__bf16)a0.x; Av[1]=(__bf16)a0.y; Av[2]=(__bf16)a0.z; Av[3]=(__bf16)a0.w;
            Av[4]=(__bf16)a1.x; Av[5]=(__bf16)a1.y; Av[6]=(__bf16)a1.z; Av[7]=(__bf16)a1.w;
          }
          Cv[ct] = __builtin_amdgcn_mfma_f32_16x16x32_bf16(Av, Bp, Cv[ct], 0, 0, 0);
        }
      }
      #pragma unroll
      for (int ct=0;ct<4;ct++)
        #pragma unroll
        for (int r=0;r<4;r++) acc[ct][r] = fmaf(rs, Cv[ct][r], acc[ct][r]);
    }
  }
  // ---- epilogue: direct coalesced stores (16 lanes consecutive q = 64 B) ----
  #pragma unroll
  for (int ct=0;ct<4;ct++) {
    #pragma unroll
    for (int r=0;r<4;r++) {
      int c = ch*64 + ct*16 + quad*4 + r;
      out[(size_t)b*196608 + (size_t)c*1536 + qt0 + qs*16 + l15] = sigmoidf_(acc[ct][r]);
    }
  }
}

extern "C" void kernel_launch(void* const* d_in, const int* in_sizes, int n_in,
                              void* d_out, int out_size, void* d_ws, size_t ws_size,
                              hipStream_t stream) {
  const float* view_cell = (const float*)d_in[0];
  const float* pose_o = (const float*)d_in[1];
  const float* pose_q = (const float*)d_in[2];
  const float* Wk1 = (const float*)d_in[3];
  const float* bk1 = (const float*)d_in[4];
  const float* Wk2 = (const float*)d_in[5];
  const float* bk2 = (const float*)d_in[6];
  const float* Wq1 = (const float*)d_in[7];
  const float* bq1 = (const float*)d_in[8];
  const float* Wq2 = (const float*)d_in[9];
  const float* bq2 = (const float*)d_in[10];
  const float* Wa1 = (const float*)d_in[11];
  const float* ba1 = (const float*)d_in[12];
  const float* Wa2 = (const float*)d_in[13];
  const float* ba2 = (const float*)d_in[14];

  float* out = (float*)d_out;
  float* out_qo = out + 6291456;
  float* out_qq = out + 6291456 + 1792;

  bf16* ws_eo   = (bf16*)((char*)d_ws + WS_EO);
  bf16* ws_w2t  = (bf16*)((char*)d_ws + WS_W2T);
  bf16* ws_w1t  = (bf16*)((char*)d_ws + WS_W1T);
  bf16* ws_wa1t = (bf16*)((char*)d_ws + WS_WA1T);
  bf16* ws_vbf  = (bf16*)((char*)d_ws + WS_VBF);

  const bool pre = ws_size >= (size_t)(WS_VBF + 256u*128u*256u*2u);
  const int vblocks = pre ? 4096 : 0;

  hipLaunchKernelGGL(k_prep, dim3(vblocks + 5), dim3(256), 0, stream,
                     view_cell, ws_vbf, pose_o, pose_q, Wk1, bk1, Wk2, bk2,
                     Wq1, bq1, Wq2, Wa1, out_qo, out_qq,
                     ws_eo, ws_w2t, ws_w1t, ws_wa1t, vblocks);

  if (pre) {
    hipLaunchKernelGGL((k_main<true>), dim3(48, 32), dim3(256), 0, stream,
                       view_cell, ws_vbf, pose_o, pose_q, ws_eo, ws_w2t,
                       ws_w1t, ws_wa1t, bq2, ba1, Wa2, ba2, out);
  } else {
    hipLaunchKernelGGL((k_main<false>), dim3(48, 32), dim3(256), 0, stream,
                       view_cell, ws_vbf, pose_o, pose_q, ws_eo, ws_w2t,
                       ws_w1t, ws_wa1t, bq2, ba1, Wa2, ba2, out);
  }
}

// Round 6
// 291.096 us; speedup vs baseline: 3.2192x; 2.2034x over previous
//
#include <hip/hip_runtime.h>
#include <hip/hip_bf16.h>

using bf16 = __hip_bfloat16;
typedef __bf16 bfrag __attribute__((ext_vector_type(8)));
typedef float  ffrag __attribute__((ext_vector_type(4)));

// Problem: B=32, N=8, Q=1536, K=256, CELL=128, EMB=32. Inputs f32, outputs f32.
// workspace layout (bytes)
#define WS_EO    0         // emb_o bf16 [256 key][32 e]                16 KB
#define WS_W2T   16384     // Wq2^T bf16 [32 e][256 h]                  16 KB
#define WS_W1T   32768     // Wq1^T bf16 [256 h][32 in-pad] (+bias k15) 16 KB
#define WS_WA1T  49152     // Wa1^T*ln2 bf16 [64 u][32 e]                4 KB
#define WS_VBF   65536     // view_cell bf16 [256 bn][128 c][256 k]     16 MB (optional)

#define LOG2E 1.44269504f
#define LN2   0.6931471805599453f

__device__ __forceinline__ float sigmoidf_(float x){ return 1.f/(1.f+__expf(-x)); }

__device__ __forceinline__ void relpose(const float* mo, const float* mq, float* o) {
  float a=mo[0],bb=mo[1],c=mo[2], d=mo[4],e=mo[5],f=mo[6], g=mo[8],h=mo[9],i9=mo[10];
  float A = e*i9-f*h, Bc = f*g-d*i9, C = d*h-e*g;
  float inv = 1.f/(a*A + bb*Bc + c*C);
  float r00=A*inv,  r01=(c*h-bb*i9)*inv, r02=(bb*f-c*e)*inv;
  float r10=Bc*inv, r11=(a*i9-c*g)*inv,  r12=(c*d-a*f)*inv;
  float r20=C*inv,  r21=(bb*g-a*h)*inv,  r22=(a*e-bb*d)*inv;
  float tx = mq[3]-mo[3], ty = mq[7]-mo[7], tz = mq[11]-mo[11];
  o[0]=r00*mq[0]+r01*mq[4]+r02*mq[8];  o[1]=r00*mq[1]+r01*mq[5]+r02*mq[9];
  o[2]=r00*mq[2]+r01*mq[6]+r02*mq[10]; o[3]=r00*tx+r01*ty+r02*tz;
  o[4]=r10*mq[0]+r11*mq[4]+r12*mq[8];  o[5]=r10*mq[1]+r11*mq[5]+r12*mq[9];
  o[6]=r10*mq[2]+r11*mq[6]+r12*mq[10]; o[7]=r10*tx+r11*ty+r12*tz;
  o[8]=r20*mq[0]+r21*mq[4]+r22*mq[8];  o[9]=r20*mq[1]+r21*mq[5]+r22*mq[9];
  o[10]=r20*mq[2]+r21*mq[6]+r22*mq[10]; o[11]=r20*tx+r21*ty+r22*tz;
}

__device__ __forceinline__ void quat7(const float* m, float* o) {
  float m00=m[0], m01=m[1], m02=m[2];
  float m10=m[4], m11=m[5], m12=m[6];
  float m20=m[8], m21=m[9], m22=m[10];
  float t,q0,q1,q2,q3;
  if (m22 < 0.f) {
    if (m00 > m11) { t=1.f+m00-m11-m22; q0=t;        q1=m01+m10; q2=m20+m02; q3=m12-m21; }
    else           { t=1.f-m00+m11-m22; q0=m01+m10; q1=t;        q2=m12+m21; q3=m20-m02; }
  } else {
    if (m00 < -m11){ t=1.f-m00-m11+m22; q0=m20+m02; q1=m12+m21; q2=t;        q3=m01-m10; }
    else           { t=1.f+m00+m11+m22; q0=m12-m21; q1=m20-m02; q2=m01-m10; q3=t;        }
  }
  float s = 0.5f / sqrtf(t);
  o[0]=m[3]; o[1]=m[7]; o[2]=m[11];
  o[3]=q0*s; o[4]=q1*s; o[5]=q2*s; o[6]=q3*s;
}

// ---------------- single prep kernel: vconv blocks + 5 parallel 1-block roles --------
__global__ void k_prep(const float* __restrict__ vc, bf16* __restrict__ vbf,
                       const float* __restrict__ pose_o, const float* __restrict__ pose_q,
                       const float* __restrict__ Wk1, const float* __restrict__ bk1,
                       const float* __restrict__ Wk2, const float* __restrict__ bk2,
                       const float* __restrict__ Wq1, const float* __restrict__ bq1,
                       const float* __restrict__ Wq2, const float* __restrict__ Wa1,
                       float* __restrict__ out_qo, float* __restrict__ out_qq,
                       bf16* __restrict__ ws_eo, bf16* __restrict__ ws_w2t,
                       bf16* __restrict__ ws_w1t, bf16* __restrict__ ws_wa1t,
                       int vblocks) {
  const int bid = blockIdx.x, tid = threadIdx.x;
  if (bid < vblocks) {   // view_cell f32 -> bf16
    int idx = (bid*256 + tid)*8;
    float4 a = *(const float4*)&vc[idx];
    float4 b = *(const float4*)&vc[idx+4];
    __bf16 o[8] __attribute__((aligned(16)));
    o[0]=(__bf16)a.x; o[1]=(__bf16)a.y; o[2]=(__bf16)a.z; o[3]=(__bf16)a.w;
    o[4]=(__bf16)b.x; o[5]=(__bf16)b.y; o[6]=(__bf16)b.z; o[7]=(__bf16)b.w;
    *(uint4*)&vbf[idx] = *(const uint4*)o;
    return;
  }
  const int role = bid - vblocks;
  if (role == 0) {          // quaternion outputs
    float mo[12];
    #pragma unroll
    for (int i=0;i<12;i++) mo[i] = pose_o[tid*12+i];
    float q7[7]; quat7(mo, q7);
    #pragma unroll
    for (int i=0;i<7;i++) out_qo[tid*7+i] = q7[i];
    if (tid < 32) {
      float mq[12];
      #pragma unroll
      for (int i=0;i<12;i++) mq[i] = pose_q[tid*12+i];
      float q7b[7]; quat7(mq, q7b);
      #pragma unroll
      for (int i=0;i<7;i++) out_qq[tid*7+i] = q7b[i];
    }
  } else if (role == 1) {   // key embeddings -> ws_eo [key][32]
    int k = tid;
    float x0 = -1.f + (float)(k>>4)*(2.f/15.f);
    float x1 = -1.f + (float)(k&15)*(2.f/15.f);
    float acc[32];
    #pragma unroll
    for (int e=0;e<32;e++) acc[e] = bk2[e];
    for (int j=0;j<128;j++) {
      float hj = fmaxf(fmaf(x0, Wk1[j], fmaf(x1, Wk1[128+j], bk1[j])), 0.f);
      #pragma unroll
      for (int u=0;u<8;u++) {
        float4 w = *(const float4*)&Wk2[j*32+u*4];
        acc[u*4+0] = fmaf(hj, w.x, acc[u*4+0]);
        acc[u*4+1] = fmaf(hj, w.y, acc[u*4+1]);
        acc[u*4+2] = fmaf(hj, w.z, acc[u*4+2]);
        acc[u*4+3] = fmaf(hj, w.w, acc[u*4+3]);
      }
    }
    #pragma unroll
    for (int e=0;e<32;e++) ws_eo[k*32+e] = __float2bfloat16(acc[e]);
  } else if (role == 2) {   // Wq2 [256h][32e] -> ws_w2t [e][h]
    int k = tid;
    #pragma unroll
    for (int u=0;u<8;u++) {
      float4 w = *(const float4*)&Wq2[k*32+u*4];
      ws_w2t[(u*4+0)*256+k] = __float2bfloat16(w.x);
      ws_w2t[(u*4+1)*256+k] = __float2bfloat16(w.y);
      ws_w2t[(u*4+2)*256+k] = __float2bfloat16(w.z);
      ws_w2t[(u*4+3)*256+k] = __float2bfloat16(w.w);
    }
  } else if (role == 3) {   // Wq1 [15][256] -> ws_w1t [h][32] with bias row k=15, 16..31 = 0
    int h = tid;
    bf16 row[32];
    #pragma unroll
    for (int i=0;i<15;i++) row[i] = __float2bfloat16(Wq1[i*256+h]);
    row[15] = __float2bfloat16(bq1[h]);
    #pragma unroll
    for (int i=16;i<32;i++) row[i] = __float2bfloat16(0.f);
    #pragma unroll
    for (int i=0;i<32;i++) ws_w1t[h*32+i] = row[i];
  } else {                  // Wa1 [32e][64u] -> ws_wa1t [u][e] * ln2 (emb is log2e-scaled)
    if (tid < 64) {
      #pragma unroll
      for (int e=0;e<32;e++) ws_wa1t[tid*32+e] = __float2bfloat16(Wa1[e*64+tid] * LN2);
    }
  }
}

// ---------------- k_main: R0 structure + deferred-P4 software pipeline ---------------
// grid (48 q-tiles, 32 b), 4 waves, lockstep barriers (B1..B4 per n; B5 elided — the
// B1 of n+1 already orders P4(n) before any n+1 writes). P4 for iteration n runs one
// iteration LATE, placed between P2(n+1) and B2(n+1): its 16 global V-loads overlap the
// barrier waits instead of sitting serially after B4 (R0's main exposed latency).
// Hidden/P buffer is ping-ponged (s_hp[2]) so P(n-1) stays alive while hidden(n) is
// written. Frag layouts (gfx950 16x16x32_bf16): A[m=l15][k=quad*8+j],
// B[k=quad*8+j][n=l15], D[m=quad*4+r][n=l15].
template<bool PRE>
__global__ void __launch_bounds__(256, 3)
k_main(const float* __restrict__ vc, const bf16* __restrict__ vbf_,
       const float* __restrict__ pose_o, const float* __restrict__ pose_q,
       const bf16* __restrict__ ws_eo_, const bf16* __restrict__ ws_w2t_,
       const bf16* __restrict__ ws_w1t_, const bf16* __restrict__ ws_wa1t_,
       const float* __restrict__ bq2,
       const float* __restrict__ ba1, const float* __restrict__ Wa2,
       const float* __restrict__ ba2,
       float* __restrict__ out) {
  __shared__ __align__(16) __bf16 s_hp[2][32*264]; // hidden(n) -> P(n), ping-pong 33792 B
  __shared__ __align__(16) __bf16 s_eqT[32*40];    // emb_q' [q][e]                2560 B
  __shared__ float s_pt[8][12];
  __shared__ float s_bw[128];        // ba1[0..63], Wa2[64..127]
  __shared__ float s_redA[2][16][4]; // mask partials [qs][q][w]
  __shared__ float s_redB[2][16][4]; // max partials
  __shared__ float s_redC[2][16][4]; // exp-sum partials
  // total ~38.8 KB -> 4 blocks/CU LDS-wise

  const __bf16* vbf  = (const __bf16*)vbf_;
  const __bf16* eo   = (const __bf16*)ws_eo_;
  const __bf16* w2t  = (const __bf16*)ws_w2t_;
  const __bf16* w1t  = (const __bf16*)ws_w1t_;
  const __bf16* wa1t = (const __bf16*)ws_wa1t_;

  const int tid  = threadIdx.x;
  const int w    = tid >> 6;
  const int lane = tid & 63;
  const int quad = lane >> 4;
  const int l15  = lane & 15;
  const int b    = blockIdx.y;
  const int qt0  = blockIdx.x * 32;

  // ---- staging ----
  if (tid < 8) {
    float mo[12], mq[12], pt[12];
    #pragma unroll
    for (int i=0;i<12;i++) mo[i] = pose_o[(b*8+tid)*12+i];
    #pragma unroll
    for (int i=0;i<12;i++) mq[i] = pose_q[b*12+i];
    relpose(mo, mq, pt);
    #pragma unroll
    for (int i=0;i<12;i++) s_pt[tid][i] = pt[i];
  }
  if (tid < 64) s_bw[tid] = ba1[tid];
  else if (tid < 128) s_bw[tid] = Wa2[tid-64];
  __syncthreads();

  // ---- hoisted n-invariant fragments / scalars (R0) ----
  bfrag w1A[4], eoA[4], waA;
  #pragma unroll
  for (int t=0;t<4;t++) {
    w1A[t] = *(const bfrag*)&w1t[((w*4+t)*16+l15)*32 + quad*8];
    eoA[t] = *(const bfrag*)&eo[((w*4+t)*16+l15)*32 + quad*8];
  }
  waA = *(const bfrag*)&wa1t[(w*16+l15)*32 + quad*8];
  const int   qs2 = w & 1, et = w >> 1;              // layer-2 combo
  const float bq2v = bq2[et*16 + l15] * LOG2E;       // log2-domain bias
  float ba1r[4], wa2r[4];
  #pragma unroll
  for (int r=0;r<4;r++) { ba1r[r] = s_bw[w*16+quad*4+r]; wa2r[r] = s_bw[64+w*16+quad*4+r]; }
  const float ba2v = ba2[0];
  float c012[2][3];
  #pragma unroll
  for (int qs=0;qs<2;qs++) {
    int qg = qt0 + qs*16 + l15;
    c012[qs][0] = (float)(qg>>8) * 0.2f;
    c012[qs][1] = -1.f + (float)((qg>>4)&15)*(2.f/15.f);
    c012[qs][2] = -1.f + (float)(qg&15)*(2.f/15.f);
  }

  float acc[2][2][4];   // [ct][qs][r]
  #pragma unroll
  for (int ct=0;ct<2;ct++)
    #pragma unroll
    for (int qs=0;qs<2;qs++)
      #pragma unroll
      for (int r=0;r<4;r++) acc[ct][qs][r] = 0.f;
  float rs_prev[2] = {0.f, 0.f};

  #pragma unroll 1
  for (int n=0; n<=8; n++) {
    __bf16* H        = s_hp[n&1];        // hidden(n) -> P(n)
    const __bf16* Hp = s_hp[(n+1)&1];    // P(n-1)
    // ---- phase 1 (n<8): hidden D[h][q] = W1^T @ X, 4 h-tiles/wave, both qs ----
    if (n < 8) {
      bfrag Bx[2];
      #pragma unroll
      for (int qs=0;qs<2;qs++) {
        #pragma unroll
        for (int j=0;j<8;j++) {
          int k = quad*8+j;
          float v = (k<12) ? s_pt[n][k<12?k:0]
                  : (k==12) ? c012[qs][0] : (k==13) ? c012[qs][1]
                  : (k==14) ? c012[qs][2] : (k==15) ? 1.f : 0.f;
          Bx[qs][j] = (__bf16)v;
        }
      }
      #pragma unroll
      for (int t=0;t<4;t++) {
        #pragma unroll
        for (int qs=0;qs<2;qs++) {
          ffrag C = {0.f,0.f,0.f,0.f};
          C = __builtin_amdgcn_mfma_f32_16x16x32_bf16(w1A[t], Bx[qs], C, 0, 0, 0);
          __bf16 p[4] __attribute__((aligned(8)));
          #pragma unroll
          for (int r=0;r<4;r++) p[r] = (__bf16)fmaxf(C[r], 0.f);
          *(uint2*)&H[(qs*16+l15)*264 + (w*4+t)*16 + quad*4] = *(const uint2*)p;
        }
      }
    }
    __syncthreads();                                   // B1
    // ---- phase 2 (n<8): layer2 D[q][e] = hidden @ W2, combo (qs2, et) ----
    if (n < 8) {
      ffrag C2 = {0.f,0.f,0.f,0.f};
      #pragma unroll
      for (int s=0;s<8;s++) {
        bfrag A  = *(const bfrag*)&H[(qs2*16+l15)*264 + s*32 + quad*8];
        bfrag Bw = *(const bfrag*)&w2t[(et*16+l15)*256 + s*32 + quad*8];
        C2 = __builtin_amdgcn_mfma_f32_16x16x32_bf16(A, Bw, C2, 0, 0, 0);
      }
      #pragma unroll
      for (int r=0;r<4;r++)
        s_eqT[(qs2*16+quad*4+r)*40 + et*16 + l15] = (__bf16)fmaf(C2[r], LOG2E, bq2v);
    }
    // ---- deferred phase 4 (n>0): vatt for n-1 — V-load latency overlaps B2..B4 ----
    if (n > 0) {
      const int bnp = b*8 + (n-1);
      ffrag Cv[2][2];
      #pragma unroll
      for (int ct=0;ct<2;ct++)
        #pragma unroll
        for (int qs=0;qs<2;qs++) Cv[ct][qs] = (ffrag){0.f,0.f,0.f,0.f};
      #pragma unroll
      for (int s=0;s<8;s++) {
        bfrag Bp0 = *(const bfrag*)&Hp[l15*264 + s*32 + quad*8];
        bfrag Bp1 = *(const bfrag*)&Hp[(16+l15)*264 + s*32 + quad*8];
        #pragma unroll
        for (int ct=0;ct<2;ct++) {
          bfrag Av;
          if (PRE) {
            Av = *(const bfrag*)&vbf[((size_t)bnp<<15) + ((2*w+ct)*16+l15)*256 + s*32 + quad*8];
          } else {
            const float* p0 = &vc[((size_t)bnp<<15) + ((2*w+ct)*16+l15)*256 + s*32 + quad*8];
            float4 a0 = *(const float4*)p0, a1 = *(const float4*)(p0+4);
            Av[0]=(__bf16)a0.x; Av[1]=(__bf16)a0.y; Av[2]=(__bf16)a0.z; Av[3]=(__bf16)a0.w;
            Av[4]=(__bf16)a1.x; Av[5]=(__bf16)a1.y; Av[6]=(__bf16)a1.z; Av[7]=(__bf16)a1.w;
          }
          Cv[ct][0] = __builtin_amdgcn_mfma_f32_16x16x32_bf16(Av, Bp0, Cv[ct][0], 0, 0, 0);
          Cv[ct][1] = __builtin_amdgcn_mfma_f32_16x16x32_bf16(Av, Bp1, Cv[ct][1], 0, 0, 0);
        }
      }
      #pragma unroll
      for (int ct=0;ct<2;ct++)
        #pragma unroll
        for (int qs=0;qs<2;qs++)
          #pragma unroll
          for (int r=0;r<4;r++) acc[ct][qs][r] = fmaf(rs_prev[qs], Cv[ct][qs][r], acc[ct][qs][r]);
    }
    if (n < 8) {
      __syncthreads();                                 // B2
      // ---- phase 3: logits D[key][q] (4 key-tiles/wave) + mask D[u][q] ----
      bfrag Bq[2];
      Bq[0] = *(const bfrag*)&s_eqT[l15*40 + quad*8];
      Bq[1] = *(const bfrag*)&s_eqT[(16+l15)*40 + quad*8];
      float S[2][4][4];
      #pragma unroll
      for (int t=0;t<4;t++) {
        #pragma unroll
        for (int qs=0;qs<2;qs++) {
          ffrag C = {0.f,0.f,0.f,0.f};
          C = __builtin_amdgcn_mfma_f32_16x16x32_bf16(eoA[t], Bq[qs], C, 0, 0, 0);
          #pragma unroll
          for (int r=0;r<4;r++) S[qs][t][r] = C[r];
        }
      }
      #pragma unroll
      for (int qs=0;qs<2;qs++) {
        ffrag Cm = {0.f,0.f,0.f,0.f};
        Cm = __builtin_amdgcn_mfma_f32_16x16x32_bf16(waA, Bq[qs], Cm, 0, 0, 0);
        float msum = 0.f;
        #pragma unroll
        for (int r=0;r<4;r++) msum += fmaxf(Cm[r] + ba1r[r], 0.f) * wa2r[r];
        msum += __shfl_xor(msum, 16);
        msum += __shfl_xor(msum, 32);
        float mx = -1e30f;
        #pragma unroll
        for (int t=0;t<4;t++)
          #pragma unroll
          for (int r=0;r<4;r++) mx = fmaxf(mx, S[qs][t][r]);
        mx = fmaxf(mx, __shfl_xor(mx, 16));
        mx = fmaxf(mx, __shfl_xor(mx, 32));
        if (quad == 0) { s_redA[qs][l15][w] = msum; s_redB[qs][l15][w] = mx; }
      }
      __syncthreads();                                 // B3
      #pragma unroll
      for (int qs=0;qs<2;qs++) {
        float rmax = fmaxf(fmaxf(s_redB[qs][l15][0], s_redB[qs][l15][1]),
                           fmaxf(s_redB[qs][l15][2], s_redB[qs][l15][3]));
        float sum = 0.f;
        #pragma unroll
        for (int t=0;t<4;t++) {
          __bf16 p[4] __attribute__((aligned(8)));
          #pragma unroll
          for (int r=0;r<4;r++) { float e = exp2f(S[qs][t][r]-rmax); sum += e; p[r] = (__bf16)e; }
          *(uint2*)&H[(qs*16+l15)*264 + (w*4+t)*16 + quad*4] = *(const uint2*)p;
        }
        sum += __shfl_xor(sum, 16);
        sum += __shfl_xor(sum, 32);
        if (quad == 0) s_redC[qs][l15][w] = sum;
      }
      __syncthreads();                                 // B4
      #pragma unroll
      for (int qs=0;qs<2;qs++) {
        float msumT = ba2v + s_redA[qs][l15][0] + s_redA[qs][l15][1]
                           + s_redA[qs][l15][2] + s_redA[qs][l15][3];
        float ssum  = s_redC[qs][l15][0] + s_redC[qs][l15][1]
                    + s_redC[qs][l15][2] + s_redC[qs][l15][3];
        rs_prev[qs] = sigmoidf_(msumT) / ssum;
      }
    }
  }
  // ---- epilogue: direct coalesced stores (16 lanes consecutive q = 64 B) ----
  #pragma unroll
  for (int ct=0;ct<2;ct++) {
    #pragma unroll
    for (int qs=0;qs<2;qs++) {
      #pragma unroll
      for (int r=0;r<4;r++) {
        int c = (2*w+ct)*16 + quad*4 + r;
        out[(size_t)b*196608 + (size_t)c*1536 + qt0 + qs*16 + l15] = sigmoidf_(acc[ct][qs][r]);
      }
    }
  }
}

extern "C" void kernel_launch(void* const* d_in, const int* in_sizes, int n_in,
                              void* d_out, int out_size, void* d_ws, size_t ws_size,
                              hipStream_t stream) {
  const float* view_cell = (const float*)d_in[0];
  const float* pose_o = (const float*)d_in[1];
  const float* pose_q = (const float*)d_in[2];
  const float* Wk1 = (const float*)d_in[3];
  const float* bk1 = (const float*)d_in[4];
  const float* Wk2 = (const float*)d_in[5];
  const float* bk2 = (const float*)d_in[6];
  const float* Wq1 = (const float*)d_in[7];
  const float* bq1 = (const float*)d_in[8];
  const float* Wq2 = (const float*)d_in[9];
  const float* bq2 = (const float*)d_in[10];
  const float* Wa1 = (const float*)d_in[11];
  const float* ba1 = (const float*)d_in[12];
  const float* Wa2 = (const float*)d_in[13];
  const float* ba2 = (const float*)d_in[14];

  float* out = (float*)d_out;
  float* out_qo = out + 6291456;
  float* out_qq = out + 6291456 + 1792;

  bf16* ws_eo   = (bf16*)((char*)d_ws + WS_EO);
  bf16* ws_w2t  = (bf16*)((char*)d_ws + WS_W2T);
  bf16* ws_w1t  = (bf16*)((char*)d_ws + WS_W1T);
  bf16* ws_wa1t = (bf16*)((char*)d_ws + WS_WA1T);
  bf16* ws_vbf  = (bf16*)((char*)d_ws + WS_VBF);

  const bool pre = ws_size >= (size_t)(WS_VBF + 256u*128u*256u*2u);
  const int vblocks = pre ? 4096 : 0;

  hipLaunchKernelGGL(k_prep, dim3(vblocks + 5), dim3(256), 0, stream,
                     view_cell, ws_vbf, pose_o, pose_q, Wk1, bk1, Wk2, bk2,
                     Wq1, bq1, Wq2, Wa1, out_qo, out_qq,
                     ws_eo, ws_w2t, ws_w1t, ws_wa1t, vblocks);

  if (pre) {
    hipLaunchKernelGGL((k_main<true>), dim3(48, 32), dim3(256), 0, stream,
                       view_cell, ws_vbf, pose_o, pose_q, ws_eo, ws_w2t,
                       ws_w1t, ws_wa1t, bq2, ba1, Wa2, ba2, out);
  } else {
    hipLaunchKernelGGL((k_main<false>), dim3(48, 32), dim3(256), 0, stream,
                       view_cell, ws_vbf, pose_o, pose_q, ws_eo, ws_w2t,
                       ws_w1t, ws_wa1t, bq2, ba1, Wa2, ba2, out);
  }
}